// Round 2
// baseline (205.091 us; speedup 1.0000x reference)
//
#include <hip/hip_runtime.h>
#include <math.h>

#define DIM 128
#define KCODES 1024
#define NROWS 65536

typedef short bf16x8 __attribute__((ext_vector_type(8)));
typedef float f32x4 __attribute__((ext_vector_type(4)));

// ---- workspace float-index layout ----
#define WS_COUNTS 0        // 1024 f: batch histogram (zeroed by k_prep)
#define WS_ESUM   1024     // 131072 f: segment sums (zeroed by k_prep)
#define WS_IOFF   132096   // 1024 int: exclusive offsets (bumped by sortscatter)
#define WS_TOTAL  133120   // 1 f
#define WS_ENORM2 133124   // 1024 f: 512 - 0.5*||e||^2
#define WS_EBF    134148   // 131072 bf16 (= 65536 float slots), 16B aligned
#define WS_WIN    461828   // 65536 int
#define WS_SORTED 527364   // 65536 int
#define WS_SCODE  592900   // 65536 int

// ---- output float layout ----
#define OFF_Q   0
#define OFF_IND 8388608
#define OFF_NCS 8454144
#define OFF_NEA 8455168
#define OFF_NE  8586240

#define LDST 136  // LDS row stride in bf16 units (128 + 8 pad)

static __device__ __forceinline__ unsigned short f2bf(float f) {
    unsigned u = __float_as_uint(f);
    unsigned r = (u + 0x7FFFu + ((u >> 16) & 1u)) >> 16;  // RTN-even
    return (unsigned short)r;
}

// ============ kernel 1: embed -> bf16 copy + shifted half-norms + ws zeroing ============
__global__ __launch_bounds__(64) void k_prep(const float* __restrict__ embed,
                                             unsigned short* __restrict__ ebf,
                                             float* __restrict__ en2,
                                             float* __restrict__ counts,
                                             float* __restrict__ esum) {
    int k = blockIdx.x;
    int l = threadIdx.x;
    if (l == 0) counts[k] = 0.0f;
    *(float2*)&esum[(size_t)k * DIM + l * 2] = (float2){0.0f, 0.0f};
    float2 v = *(const float2*)&embed[(size_t)k * DIM + l * 2];
    ushort2 b;
    b.x = f2bf(v.x);
    b.y = f2bf(v.y);
    *(ushort2*)&ebf[k * DIM + l * 2] = b;
    float s = v.x * v.x + v.y * v.y;
    #pragma unroll
    for (int off = 32; off; off >>= 1) s += __shfl_xor(s, off);
    if (l == 0) en2[k] = 512.0f - 0.5f * s;
}

// ============ kernel 2: fused scoring + rescore + hist + quantize ============
// Occupancy rework vs prev round (was 74KB LDS -> 2 blk/CU, all pipes <31% busy):
//  - A-fragments are ct-invariant -> hoisted to 64 VGPRs once; ct-loop LDS reads halve.
//  - xbuf dead during ct loop -> ONE union buffer serves x-staging, e-tiles,
//    merge scratch, and histogram. LDS 74.2KB -> 39.4KB -> 3 blocks/CU.
//  - code-columns chunked (acc[4][2], two passes/ct) to hold VGPR <= ~160 so
//    __launch_bounds__(256,3) doesn't spill.
__global__ __launch_bounds__(256, 3) void k_fused(const float* __restrict__ x,
                                                  const float* __restrict__ embed,
                                                  const unsigned short* __restrict__ ebf,
                                                  const float* __restrict__ en2g,
                                                  int* __restrict__ win_g,
                                                  float* __restrict__ counts,
                                                  float* __restrict__ out) {
    __shared__ unsigned short buf[128 * LDST];  // union: xbuf | ebuf | scratch+hist
    __shared__ float en2s[KCODES];
    __shared__ int winS[128];

    const int tid = threadIdx.x;
    const int row0 = blockIdx.x * 128;

    #pragma unroll
    for (int i = 0; i < 4; ++i) en2s[i * 256 + tid] = en2g[i * 256 + tid];

    // ---- stage x tile (fp32 -> bf16) into buf ----
    #pragma unroll
    for (int i = 0; i < 16; ++i) {
        int idx4 = i * 256 + tid;
        int lin = idx4 * 4;
        int r = lin >> 7, d = lin & 127;
        float4 v = *(const float4*)&x[(size_t)(row0 + r) * DIM + d];
        ushort4 b;
        b.x = f2bf(v.x); b.y = f2bf(v.y); b.z = f2bf(v.z); b.w = f2bf(v.w);
        *(ushort4*)&buf[r * LDST + d] = b;
    }
    __syncthreads();  // x tile visible

    const int lane = tid & 63;
    const int wv = tid >> 6;
    const int ch = wv & 1;
    const int rh = (wv >> 1) * 64;
    const int l15 = lane & 15;
    const int q = lane >> 4;

    // ---- hoist A-fragments (ct-invariant) into registers ----
    bf16x8 af[4][4];  // [ks][rt]
    #pragma unroll
    for (int ks = 0; ks < 4; ++ks)
        #pragma unroll
        for (int t = 0; t < 4; ++t)
            af[ks][t] = *(const bf16x8*)&buf[(rh + t * 16 + l15) * LDST + ks * 32 + q * 8];
    __syncthreads();  // all af reads done; buf may be overwritten with e-tiles

    float m1[4][4], m2[4][4];
    #pragma unroll
    for (int a = 0; a < 4; ++a)
        #pragma unroll
        for (int b = 0; b < 4; ++b) { m1[a][b] = 0.0f; m2[a][b] = 0.0f; }

    for (int ct = 0; ct < 8; ++ct) {
        const int c0 = ct * 128;
        #pragma unroll
        for (int i = 0; i < 8; ++i) {
            int idx8 = i * 256 + tid;
            int r = idx8 >> 4;
            int d = (idx8 & 15) * 8;
            uint4 v = *(const uint4*)&ebf[(size_t)(c0 + r) * DIM + d];
            *(uint4*)&buf[r * LDST + d] = v;
        }
        __syncthreads();

        #pragma unroll
        for (int clh = 0; clh < 2; ++clh) {
            // C-init = en2 (folds the norm add into the MFMA for free)
            f32x4 acc[4][2];
            #pragma unroll
            for (int c2 = 0; c2 < 2; ++c2) {
                float en = en2s[c0 + ch * 64 + clh * 32 + c2 * 16 + l15];
                #pragma unroll
                for (int rt = 0; rt < 4; ++rt) acc[rt][c2] = (f32x4){en, en, en, en};
            }

            #pragma unroll
            for (int ks = 0; ks < 4; ++ks) {
                bf16x8 bfr[2];
                #pragma unroll
                for (int c2 = 0; c2 < 2; ++c2)
                    bfr[c2] = *(const bf16x8*)&buf[(ch * 64 + clh * 32 + c2 * 16 + l15) * LDST +
                                                   ks * 32 + q * 8];
                #pragma unroll
                for (int rt = 0; rt < 4; ++rt)
                    #pragma unroll
                    for (int c2 = 0; c2 < 2; ++c2)
                        acc[rt][c2] = __builtin_amdgcn_mfma_f32_16x16x32_bf16(af[ks][rt], bfr[c2],
                                                                              acc[rt][c2], 0, 0, 0);
            }

            #pragma unroll
            for (int c2 = 0; c2 < 2; ++c2) {
                unsigned cu = (unsigned)(c0 + ch * 64 + clh * 32 + c2 * 16 + l15);
                #pragma unroll
                for (int rt = 0; rt < 4; ++rt)
                    #pragma unroll
                    for (int rg = 0; rg < 4; ++rg) {
                        float s = acc[rt][c2][rg];
                        float kf = __uint_as_float((__float_as_uint(s) & ~1023u) | cu);
                        // top-2 in 2 ops: m2 = med3(m1_old, m2, kf); m1 = max(m1, kf)
                        m2[rt][rg] = __builtin_amdgcn_fmed3f(m1[rt][rg], m2[rt][rg], kf);
                        m1[rt][rg] = fmaxf(m1[rt][rg], kf);
                    }
            }
        }
        __syncthreads();  // all bf reads of this tile done before next stage
    }

    // buf is free again: floats [0,512) = merge scratch, [512,1536) = histogram
    float* scratch = (float*)buf;
    unsigned* hist = (unsigned*)buf + 512;

    #pragma unroll
    for (int rt = 0; rt < 4; ++rt)
        #pragma unroll
        for (int rg = 0; rg < 4; ++rg) {
            float a1 = m1[rt][rg], a2 = m2[rt][rg];
            #pragma unroll
            for (int off = 1; off <= 8; off <<= 1) {
                float o1 = __shfl_xor(a1, off);
                float o2 = __shfl_xor(a2, off);
                float t = fmaxf(a2, o2);
                a2 = __builtin_amdgcn_fmed3f(a1, o1, t);
                a1 = fmaxf(a1, o1);
            }
            if (l15 == 0) {
                int row = rh + rt * 16 + q * 4 + rg;
                scratch[row * 4 + ch * 2 + 0] = a1;
                scratch[row * 4 + ch * 2 + 1] = a2;
            }
        }

    #pragma unroll
    for (int i = 0; i < 4; ++i) hist[i * 256 + tid] = 0u;
    __syncthreads();  // S1: scratch + hist-zero visible

    // ---- fp64 exact rescore: 16 lanes/row, 8 rows per lane-group ----
    {
        const int sub = tid & 15;
        const int g = tid >> 4;
        #pragma unroll 2
        for (int rr = 0; rr < 8; ++rr) {
            const int lrow = g * 8 + rr;
            const float* sp = &scratch[lrow * 4];
            int ci[4];
            ci[0] = (int)(__float_as_uint(sp[0]) & 1023u);
            ci[1] = (int)(__float_as_uint(sp[1]) & 1023u);
            ci[2] = (int)(__float_as_uint(sp[2]) & 1023u);
            ci[3] = (int)(__float_as_uint(sp[3]) & 1023u);

            const float* xr = &x[(size_t)(row0 + lrow) * DIM + sub * 4];
            float4 xa = *(const float4*)xr;
            float4 xb = *(const float4*)(xr + 64);

            double d[4];
            #pragma unroll
            for (int j = 0; j < 4; ++j) {
                const float* er = &embed[(size_t)ci[j] * DIM + sub * 4];
                float4 ea4 = *(const float4*)er;
                float4 eb4 = *(const float4*)(er + 64);
                double t0 = (double)xa.x - (double)ea4.x;
                double t1 = (double)xa.y - (double)ea4.y;
                double t2 = (double)xa.z - (double)ea4.z;
                double t3 = (double)xa.w - (double)ea4.w;
                double t4 = (double)xb.x - (double)eb4.x;
                double t5 = (double)xb.y - (double)eb4.y;
                double t6 = (double)xb.z - (double)eb4.z;
                double t7 = (double)xb.w - (double)eb4.w;
                d[j] = ((t0 * t0 + t1 * t1) + (t2 * t2 + t3 * t3)) +
                       ((t4 * t4 + t5 * t5) + (t6 * t6 + t7 * t7));
            }
            #pragma unroll
            for (int off = 1; off <= 8; off <<= 1) {
                #pragma unroll
                for (int j = 0; j < 4; ++j) d[j] += __shfl_xor(d[j], off);
            }

            int win = ci[0];
            double dw = d[0];
            #pragma unroll
            for (int j = 1; j < 4; ++j) {
                bool b = (d[j] < dw) || (d[j] == dw && ci[j] < win);
                dw = b ? d[j] : dw;
                win = b ? ci[j] : win;
            }
            if (sub == 0) winS[lrow] = win;
        }
    }
    __syncthreads();  // S2: winS visible

    // ---- hist atomics + ind + win writes ----
    if (tid < 128) {
        int w = winS[tid];
        atomicAdd(&hist[w], 1u);
        win_g[row0 + tid] = w;
        out[OFF_IND + row0 + tid] = (float)w;
    }

    // ---- quantize gather + coalesced write (32 rows per wave) ----
    #pragma unroll 4
    for (int i = 0; i < 32; ++i) {
        int lrow = wv * 32 + i;
        int w = winS[lrow];  // wave-uniform
        float2 v = *(const float2*)&embed[(size_t)w * DIM + lane * 2];
        *(float2*)&out[OFF_Q + (size_t)(row0 + lrow) * DIM + lane * 2] = v;
    }

    __syncthreads();  // S3: hist atomics done
    #pragma unroll
    for (int i = 0; i < 4; ++i) {
        unsigned c = hist[i * 256 + tid];
        if (c) atomicAdd(&counts[i * 256 + tid], (float)c);
    }
}

// ============ kernel 4: shuffle-scan offsets + new_cluster_size + total ============
__global__ __launch_bounds__(1024) void k_offsets(const float* __restrict__ cs,
                                                  float* __restrict__ out,
                                                  float* __restrict__ ws) {
    __shared__ int wsum[16];
    __shared__ float wtot[16];
    const float* counts = ws + WS_COUNTS;
    int* ioff = (int*)(ws + WS_IOFF);

    int t = threadIdx.x;
    int lane = t & 63, w = t >> 6;
    float cf = counts[t];
    int c = (int)cf;
    float ncs = cs[t] * 0.99f + 0.01f * cf;
    out[OFF_NCS + t] = ncs;

    int v = c;
    #pragma unroll
    for (int off = 1; off < 64; off <<= 1) {
        int o = __shfl_up(v, off);
        if (lane >= off) v += o;
    }
    float nf = ncs;
    #pragma unroll
    for (int off = 32; off; off >>= 1) nf += __shfl_xor(nf, off);

    if (lane == 63) wsum[w] = v;
    if (lane == 0) wtot[w] = nf;
    __syncthreads();

    int base = 0;
    for (int i = 0; i < w; ++i) base += wsum[i];
    ioff[t] = base + v - c;

    if (t == 0) {
        float tt = 0.f;
        for (int i = 0; i < 16; ++i) tt += wtot[i];
        ws[WS_TOTAL] = tt;
    }
}

// ============ kernel 5: scatter rows into code-sorted order ============
__global__ __launch_bounds__(256) void k_sortscatter(const int* __restrict__ win_arr,
                                                     int* __restrict__ ioff,
                                                     int* __restrict__ sorted,
                                                     int* __restrict__ scode) {
    int row = blockIdx.x * 256 + threadIdx.x;
    int w = win_arr[row];
    int pos = atomicAdd(&ioff[w], 1);
    sorted[pos] = row;
    scode[pos] = w;
}

// ============ kernel 6: chunked run-length segment sum (skew-proof) ============
__global__ __launch_bounds__(256) void k_segsum(const float* __restrict__ x,
                                                const int* __restrict__ sorted,
                                                const int* __restrict__ scode,
                                                float* __restrict__ esum) {
    const int lane = threadIdx.x & 63;
    const int wv = threadIdx.x >> 6;
    const int base = blockIdx.x * 64 + wv * 16;

    int p = base + (lane & 15);
    int srow = sorted[p];
    int sc = scode[p];

    float ax = 0.f, ay = 0.f;
    int cur = __shfl(sc, 0);

    #pragma unroll
    for (int j = 0; j < 16; ++j) {
        int row = __shfl(srow, j);
        int c = __shfl(sc, j);
        if (c != cur) {
            atomicAdd(&esum[cur * DIM + lane * 2], ax);
            atomicAdd(&esum[cur * DIM + lane * 2 + 1], ay);
            ax = 0.f; ay = 0.f;
            cur = c;
        }
        float2 v = *(const float2*)&x[(size_t)row * DIM + lane * 2];
        ax += v.x;
        ay += v.y;
    }
    atomicAdd(&esum[cur * DIM + lane * 2], ax);
    atomicAdd(&esum[cur * DIM + lane * 2 + 1], ay);
}

// ============ kernel 7: new_embed_avg + new_embed ============
__global__ __launch_bounds__(256) void k_embed(const float* __restrict__ ea,
                                               const float* __restrict__ ws,
                                               float* __restrict__ out) {
    int i = blockIdx.x * 256 + threadIdx.x;
    int k = i >> 7;
    float nea = ea[i] * 0.99f + 0.01f * ws[WS_ESUM + i];
    out[OFF_NEA + i] = nea;
    float total = ws[WS_TOTAL];
    float ncs = out[OFF_NCS + k];
    float sm = (ncs + 1e-5f) / (total + 1024.0f * 1e-5f);
    out[OFF_NE + i] = nea / (sm * total);
}

extern "C" void kernel_launch(void* const* d_in, const int* in_sizes, int n_in,
                              void* d_out, int out_size, void* d_ws, size_t ws_size,
                              hipStream_t stream) {
    const float* x     = (const float*)d_in[0];
    const float* embed = (const float*)d_in[1];
    const float* cs    = (const float*)d_in[2];
    const float* ea    = (const float*)d_in[3];
    float* out = (float*)d_out;
    float* ws  = (float*)d_ws;

    k_prep<<<KCODES, 64, 0, stream>>>(embed, (unsigned short*)(ws + WS_EBF),
                                      ws + WS_ENORM2, ws + WS_COUNTS, ws + WS_ESUM);
    k_fused<<<NROWS / 128, 256, 0, stream>>>(x, embed,
                                             (const unsigned short*)(ws + WS_EBF),
                                             ws + WS_ENORM2, (int*)(ws + WS_WIN),
                                             ws + WS_COUNTS, out);
    k_offsets<<<1, 1024, 0, stream>>>(cs, out, ws);
    k_sortscatter<<<NROWS / 256, 256, 0, stream>>>((const int*)(ws + WS_WIN),
                                                   (int*)(ws + WS_IOFF),
                                                   (int*)(ws + WS_SORTED),
                                                   (int*)(ws + WS_SCODE));
    k_segsum<<<1024, 256, 0, stream>>>(x, (const int*)(ws + WS_SORTED),
                                       (const int*)(ws + WS_SCODE), ws + WS_ESUM);
    k_embed<<<131072 / 256, 256, 0, stream>>>(ea, ws, out);
}

// Round 3
// 186.733 us; speedup vs baseline: 1.0983x; 1.0983x over previous
//
#include <hip/hip_runtime.h>
#include <math.h>

#define DIM 128
#define KCODES 1024
#define NROWS 65536

typedef short bf16x8 __attribute__((ext_vector_type(8)));
typedef float f32x4 __attribute__((ext_vector_type(4)));

// ---- workspace float-index layout ----
#define WS_COUNTS 0        // 1024 f: batch histogram (zeroed by k_prep)
#define WS_ESUM   1024     // 131072 f: segment sums (zeroed by k_prep)
#define WS_IOFF   132096   // 1024 int: exclusive offsets (bumped by sortscatter)
#define WS_TOTAL  133120   // 1 f
#define WS_ENORM2 133124   // 1024 f: 512 - 0.5*||e||^2
#define WS_EBF    134148   // 131072 bf16 (= 65536 float slots), 16B aligned
#define WS_WIN    461828   // 65536 int
#define WS_SORTED 527364   // 65536 int
#define WS_SCODE  592900   // 65536 int

// ---- output float layout ----
#define OFF_Q   0
#define OFF_IND 8388608
#define OFF_NCS 8454144
#define OFF_NEA 8455168
#define OFF_NE  8586240

#define LDST 136  // LDS row stride in bf16 units (128 + 8 pad)

static __device__ __forceinline__ unsigned short f2bf(float f) {
    unsigned u = __float_as_uint(f);
    unsigned r = (u + 0x7FFFu + ((u >> 16) & 1u)) >> 16;  // RTN-even
    return (unsigned short)r;
}

// ============ kernel 1: embed -> bf16 copy + shifted half-norms + ws zeroing ============
__global__ __launch_bounds__(64) void k_prep(const float* __restrict__ embed,
                                             unsigned short* __restrict__ ebf,
                                             float* __restrict__ en2,
                                             float* __restrict__ counts,
                                             float* __restrict__ esum) {
    int k = blockIdx.x;
    int l = threadIdx.x;
    if (l == 0) counts[k] = 0.0f;
    *(float2*)&esum[(size_t)k * DIM + l * 2] = (float2){0.0f, 0.0f};
    float2 v = *(const float2*)&embed[(size_t)k * DIM + l * 2];
    ushort2 b;
    b.x = f2bf(v.x);
    b.y = f2bf(v.y);
    *(ushort2*)&ebf[k * DIM + l * 2] = b;
    float s = v.x * v.x + v.y * v.y;
    #pragma unroll
    for (int off = 32; off; off >>= 1) s += __shfl_xor(s, off);
    if (l == 0) en2[k] = 512.0f - 0.5f * s;
}

// ============ kernel 2: fused scoring + rescore + hist + quantize ============
// Round-2 post-mortem: occupancy was GRID-limited (512 blocks / 256 CU = 2 blk/CU),
// so shrinking LDS did nothing; clh-chunking serialized MFMA and regressed 57->74us.
// This round:
//  - 512 threads/block (8 waves): 2 blk/CU x 8 waves = 16 waves/CU = 4 waves/SIMD.
//    __launch_bounds__(512,4) pins VGPR <= 128 (round-2 compiled at 84; fits).
//  - each wave: 32 rows x 64 codes. af[4][2] hoisted (ct-invariant), acc[2][4] full-width.
//  - ping-pong e-tile double buffer, ONE barrier per ct (was 2): next-tile global
//    loads issue before MFMA (latency hides under compute), ds_write to the other
//    buffer after, single barrier. Read/write always touch different buffers.
__global__ __launch_bounds__(512, 4) void k_fused(const float* __restrict__ x,
                                                  const float* __restrict__ embed,
                                                  const unsigned short* __restrict__ ebf,
                                                  const float* __restrict__ en2g,
                                                  int* __restrict__ win_g,
                                                  float* __restrict__ counts,
                                                  float* __restrict__ out) {
    __shared__ unsigned short buf[2][128 * LDST];  // ping-pong e-tiles; buf[0] stages x first
    __shared__ float en2s[KCODES];
    __shared__ int winS[128];

    const int tid = threadIdx.x;  // 0..511
    const int row0 = blockIdx.x * 128;

    #pragma unroll
    for (int i = 0; i < 2; ++i) en2s[i * 512 + tid] = en2g[i * 512 + tid];

    // ---- stage x tile (fp32 -> bf16) into buf[0] ----
    #pragma unroll
    for (int i = 0; i < 8; ++i) {
        int idx4 = i * 512 + tid;
        int lin = idx4 * 4;
        int r = lin >> 7, d = lin & 127;
        float4 v = *(const float4*)&x[(size_t)(row0 + r) * DIM + d];
        ushort4 b;
        b.x = f2bf(v.x); b.y = f2bf(v.y); b.z = f2bf(v.z); b.w = f2bf(v.w);
        *(ushort4*)&buf[0][r * LDST + d] = b;
    }
    __syncthreads();  // x tile visible

    const int lane = tid & 63;
    const int wv = tid >> 6;        // 0..7
    const int ch = wv & 1;          // code half (64 codes)
    const int rh = (wv >> 1) * 32;  // row base (32 rows per wave)
    const int l15 = lane & 15;
    const int q = lane >> 4;

    // ---- hoist A-fragments (ct-invariant) from buf[0] ----
    bf16x8 af[4][2];  // [ks][rt]
    #pragma unroll
    for (int ks = 0; ks < 4; ++ks)
        #pragma unroll
        for (int t = 0; t < 2; ++t)
            af[ks][t] = *(const bf16x8*)&buf[0][(rh + t * 16 + l15) * LDST + ks * 32 + q * 8];

    // ---- prologue: tile0 -> regs -> buf[1] (no conflict with af reads of buf[0]) ----
    uint4 er[4];
    #pragma unroll
    for (int i = 0; i < 4; ++i) {
        int idx8 = i * 512 + tid;
        int r = idx8 >> 4;
        int d = (idx8 & 15) * 8;
        er[i] = *(const uint4*)&ebf[(size_t)r * DIM + d];
    }
    #pragma unroll
    for (int i = 0; i < 4; ++i) {
        int idx8 = i * 512 + tid;
        int r = idx8 >> 4;
        int d = (idx8 & 15) * 8;
        *(uint4*)&buf[1][r * LDST + d] = er[i];
    }
    __syncthreads();  // tile0 ready; af reads of buf[0] complete

    float m1[2][4], m2[2][4];
    #pragma unroll
    for (int a = 0; a < 2; ++a)
        #pragma unroll
        for (int b = 0; b < 4; ++b) { m1[a][b] = 0.0f; m2[a][b] = 0.0f; }

    for (int ct = 0; ct < 8; ++ct) {
        const int c0 = ct * 128;
        const unsigned short* cbuf = buf[1 ^ (ct & 1)];  // tile ct lives here

        // issue next-tile loads early (latency hides under MFMA + tracking)
        if (ct < 7) {
            #pragma unroll
            for (int i = 0; i < 4; ++i) {
                int idx8 = i * 512 + tid;
                int r = idx8 >> 4;
                int d = (idx8 & 15) * 8;
                er[i] = *(const uint4*)&ebf[(size_t)(c0 + 128 + r) * DIM + d];
            }
        }

        // C-init = en2 (folds norm add into MFMA)
        f32x4 acc[2][4];
        #pragma unroll
        for (int cl = 0; cl < 4; ++cl) {
            float en = en2s[c0 + ch * 64 + cl * 16 + l15];
            #pragma unroll
            for (int rt = 0; rt < 2; ++rt) acc[rt][cl] = (f32x4){en, en, en, en};
        }

        #pragma unroll
        for (int ks = 0; ks < 4; ++ks) {
            bf16x8 bfr[4];
            #pragma unroll
            for (int cl = 0; cl < 4; ++cl)
                bfr[cl] = *(const bf16x8*)&cbuf[(ch * 64 + cl * 16 + l15) * LDST + ks * 32 + q * 8];
            #pragma unroll
            for (int rt = 0; rt < 2; ++rt)
                #pragma unroll
                for (int cl = 0; cl < 4; ++cl)
                    acc[rt][cl] = __builtin_amdgcn_mfma_f32_16x16x32_bf16(af[ks][rt], bfr[cl],
                                                                          acc[rt][cl], 0, 0, 0);
        }

        // top-2 tracking: 2 ops/value (med3 + max)
        #pragma unroll
        for (int cl = 0; cl < 4; ++cl) {
            unsigned cu = (unsigned)(c0 + ch * 64 + cl * 16 + l15);
            #pragma unroll
            for (int rt = 0; rt < 2; ++rt)
                #pragma unroll
                for (int rg = 0; rg < 4; ++rg) {
                    float s = acc[rt][cl][rg];
                    float kf = __uint_as_float((__float_as_uint(s) & ~1023u) | cu);
                    m2[rt][rg] = __builtin_amdgcn_fmed3f(m1[rt][rg], m2[rt][rg], kf);
                    m1[rt][rg] = fmaxf(m1[rt][rg], kf);
                }
        }

        // write next tile into the buffer we just finished reading FROM last ct
        // (reads of buf[ct&1] ended at the previous barrier -> safe)
        if (ct < 7) {
            unsigned short* nbuf = buf[ct & 1];
            #pragma unroll
            for (int i = 0; i < 4; ++i) {
                int idx8 = i * 512 + tid;
                int r = idx8 >> 4;
                int d = (idx8 & 15) * 8;
                *(uint4*)&nbuf[r * LDST + d] = er[i];
            }
        }
        __syncthreads();  // next tile ready / this tile's reads complete
    }

    // buf free: floats [0,512) = merge scratch, [512,1536) = histogram
    float* scratch = (float*)buf[0];
    unsigned* hist = (unsigned*)buf[0] + 512;

    #pragma unroll
    for (int rt = 0; rt < 2; ++rt)
        #pragma unroll
        for (int rg = 0; rg < 4; ++rg) {
            float a1 = m1[rt][rg], a2 = m2[rt][rg];
            #pragma unroll
            for (int off = 1; off <= 8; off <<= 1) {
                float o1 = __shfl_xor(a1, off);
                float o2 = __shfl_xor(a2, off);
                float t = fmaxf(a2, o2);
                a2 = __builtin_amdgcn_fmed3f(a1, o1, t);
                a1 = fmaxf(a1, o1);
            }
            if (l15 == 0) {
                int row = rh + rt * 16 + q * 4 + rg;
                scratch[row * 4 + ch * 2 + 0] = a1;
                scratch[row * 4 + ch * 2 + 1] = a2;
            }
        }

    #pragma unroll
    for (int i = 0; i < 2; ++i) hist[i * 512 + tid] = 0u;
    __syncthreads();  // S1: scratch + hist-zero visible

    // ---- fp64 exact rescore: 16 lanes/row, 32 rows in flight, 4 passes ----
    {
        const int sub = tid & 15;
        const int g = tid >> 4;  // 0..31
        #pragma unroll 2
        for (int rr = 0; rr < 4; ++rr) {
            const int lrow = g * 4 + rr;
            const float* sp = &scratch[lrow * 4];
            int ci[4];
            ci[0] = (int)(__float_as_uint(sp[0]) & 1023u);
            ci[1] = (int)(__float_as_uint(sp[1]) & 1023u);
            ci[2] = (int)(__float_as_uint(sp[2]) & 1023u);
            ci[3] = (int)(__float_as_uint(sp[3]) & 1023u);

            const float* xr = &x[(size_t)(row0 + lrow) * DIM + sub * 4];
            float4 xa = *(const float4*)xr;
            float4 xb = *(const float4*)(xr + 64);

            double d[4];
            #pragma unroll
            for (int j = 0; j < 4; ++j) {
                const float* er2 = &embed[(size_t)ci[j] * DIM + sub * 4];
                float4 ea4 = *(const float4*)er2;
                float4 eb4 = *(const float4*)(er2 + 64);
                double t0 = (double)xa.x - (double)ea4.x;
                double t1 = (double)xa.y - (double)ea4.y;
                double t2 = (double)xa.z - (double)ea4.z;
                double t3 = (double)xa.w - (double)ea4.w;
                double t4 = (double)xb.x - (double)eb4.x;
                double t5 = (double)xb.y - (double)eb4.y;
                double t6 = (double)xb.z - (double)eb4.z;
                double t7 = (double)xb.w - (double)eb4.w;
                d[j] = ((t0 * t0 + t1 * t1) + (t2 * t2 + t3 * t3)) +
                       ((t4 * t4 + t5 * t5) + (t6 * t6 + t7 * t7));
            }
            #pragma unroll
            for (int off = 1; off <= 8; off <<= 1) {
                #pragma unroll
                for (int j = 0; j < 4; ++j) d[j] += __shfl_xor(d[j], off);
            }

            int win = ci[0];
            double dw = d[0];
            #pragma unroll
            for (int j = 1; j < 4; ++j) {
                bool b = (d[j] < dw) || (d[j] == dw && ci[j] < win);
                dw = b ? d[j] : dw;
                win = b ? ci[j] : win;
            }
            if (sub == 0) winS[lrow] = win;
        }
    }
    __syncthreads();  // S2: winS visible

    // ---- hist atomics + ind + win writes ----
    if (tid < 128) {
        int w = winS[tid];
        atomicAdd(&hist[w], 1u);
        win_g[row0 + tid] = w;
        out[OFF_IND + row0 + tid] = (float)w;
    }

    // ---- quantize gather + coalesced write (16 rows per wave) ----
    #pragma unroll 4
    for (int i = 0; i < 16; ++i) {
        int lrow = wv * 16 + i;
        int w = winS[lrow];  // wave-uniform
        float2 v = *(const float2*)&embed[(size_t)w * DIM + lane * 2];
        *(float2*)&out[OFF_Q + (size_t)(row0 + lrow) * DIM + lane * 2] = v;
    }

    __syncthreads();  // S3: hist atomics done
    #pragma unroll
    for (int i = 0; i < 2; ++i) {
        unsigned c = hist[i * 512 + tid];
        if (c) atomicAdd(&counts[i * 512 + tid], (float)c);
    }
}

// ============ kernel 4: shuffle-scan offsets + new_cluster_size + total ============
__global__ __launch_bounds__(1024) void k_offsets(const float* __restrict__ cs,
                                                  float* __restrict__ out,
                                                  float* __restrict__ ws) {
    __shared__ int wsum[16];
    __shared__ float wtot[16];
    const float* counts = ws + WS_COUNTS;
    int* ioff = (int*)(ws + WS_IOFF);

    int t = threadIdx.x;
    int lane = t & 63, w = t >> 6;
    float cf = counts[t];
    int c = (int)cf;
    float ncs = cs[t] * 0.99f + 0.01f * cf;
    out[OFF_NCS + t] = ncs;

    int v = c;
    #pragma unroll
    for (int off = 1; off < 64; off <<= 1) {
        int o = __shfl_up(v, off);
        if (lane >= off) v += o;
    }
    float nf = ncs;
    #pragma unroll
    for (int off = 32; off; off >>= 1) nf += __shfl_xor(nf, off);

    if (lane == 63) wsum[w] = v;
    if (lane == 0) wtot[w] = nf;
    __syncthreads();

    int base = 0;
    for (int i = 0; i < w; ++i) base += wsum[i];
    ioff[t] = base + v - c;

    if (t == 0) {
        float tt = 0.f;
        for (int i = 0; i < 16; ++i) tt += wtot[i];
        ws[WS_TOTAL] = tt;
    }
}

// ============ kernel 5: scatter rows into code-sorted order ============
__global__ __launch_bounds__(256) void k_sortscatter(const int* __restrict__ win_arr,
                                                     int* __restrict__ ioff,
                                                     int* __restrict__ sorted,
                                                     int* __restrict__ scode) {
    int row = blockIdx.x * 256 + threadIdx.x;
    int w = win_arr[row];
    int pos = atomicAdd(&ioff[w], 1);
    sorted[pos] = row;
    scode[pos] = w;
}

// ============ kernel 6: chunked run-length segment sum (skew-proof) ============
__global__ __launch_bounds__(256) void k_segsum(const float* __restrict__ x,
                                                const int* __restrict__ sorted,
                                                const int* __restrict__ scode,
                                                float* __restrict__ esum) {
    const int lane = threadIdx.x & 63;
    const int wv = threadIdx.x >> 6;
    const int base = blockIdx.x * 64 + wv * 16;

    int p = base + (lane & 15);
    int srow = sorted[p];
    int sc = scode[p];

    float ax = 0.f, ay = 0.f;
    int cur = __shfl(sc, 0);

    #pragma unroll
    for (int j = 0; j < 16; ++j) {
        int row = __shfl(srow, j);
        int c = __shfl(sc, j);
        if (c != cur) {
            atomicAdd(&esum[cur * DIM + lane * 2], ax);
            atomicAdd(&esum[cur * DIM + lane * 2 + 1], ay);
            ax = 0.f; ay = 0.f;
            cur = c;
        }
        float2 v = *(const float2*)&x[(size_t)row * DIM + lane * 2];
        ax += v.x;
        ay += v.y;
    }
    atomicAdd(&esum[cur * DIM + lane * 2], ax);
    atomicAdd(&esum[cur * DIM + lane * 2 + 1], ay);
}

// ============ kernel 7: new_embed_avg + new_embed ============
__global__ __launch_bounds__(256) void k_embed(const float* __restrict__ ea,
                                               const float* __restrict__ ws,
                                               float* __restrict__ out) {
    int i = blockIdx.x * 256 + threadIdx.x;
    int k = i >> 7;
    float nea = ea[i] * 0.99f + 0.01f * ws[WS_ESUM + i];
    out[OFF_NEA + i] = nea;
    float total = ws[WS_TOTAL];
    float ncs = out[OFF_NCS + k];
    float sm = (ncs + 1e-5f) / (total + 1024.0f * 1e-5f);
    out[OFF_NE + i] = nea / (sm * total);
}

extern "C" void kernel_launch(void* const* d_in, const int* in_sizes, int n_in,
                              void* d_out, int out_size, void* d_ws, size_t ws_size,
                              hipStream_t stream) {
    const float* x     = (const float*)d_in[0];
    const float* embed = (const float*)d_in[1];
    const float* cs    = (const float*)d_in[2];
    const float* ea    = (const float*)d_in[3];
    float* out = (float*)d_out;
    float* ws  = (float*)d_ws;

    k_prep<<<KCODES, 64, 0, stream>>>(embed, (unsigned short*)(ws + WS_EBF),
                                      ws + WS_ENORM2, ws + WS_COUNTS, ws + WS_ESUM);
    k_fused<<<NROWS / 128, 512, 0, stream>>>(x, embed,
                                             (const unsigned short*)(ws + WS_EBF),
                                             ws + WS_ENORM2, (int*)(ws + WS_WIN),
                                             ws + WS_COUNTS, out);
    k_offsets<<<1, 1024, 0, stream>>>(cs, out, ws);
    k_sortscatter<<<NROWS / 256, 256, 0, stream>>>((const int*)(ws + WS_WIN),
                                                   (int*)(ws + WS_IOFF),
                                                   (int*)(ws + WS_SORTED),
                                                   (int*)(ws + WS_SCODE));
    k_segsum<<<1024, 256, 0, stream>>>(x, (const int*)(ws + WS_SORTED),
                                       (const int*)(ws + WS_SCODE), ws + WS_ESUM);
    k_embed<<<131072 / 256, 256, 0, stream>>>(ea, ws, out);
}

// Round 4
// 162.084 us; speedup vs baseline: 1.2653x; 1.1521x over previous
//
#include <hip/hip_runtime.h>
#include <math.h>

#define DIM 128
#define KCODES 1024
#define NROWS 65536

typedef short bf16x8 __attribute__((ext_vector_type(8)));
typedef float f32x4 __attribute__((ext_vector_type(4)));

// ---- workspace float-index layout ----
#define WS_COUNTS 0        // 1024 f: batch histogram (zeroed by k_prep)
#define WS_ESUM   1024     // 131072 f: segment sums (zeroed by k_prep)
#define WS_IOFF   132096   // 1024 int: exclusive offsets (bumped by sortscatter)
#define WS_TOTAL  133120   // 1 f
#define WS_ENORM2 133124   // 1024 f: 512 - 0.5*||e||^2
#define WS_EBF    134148   // 131072 bf16 (= 65536 float slots), 16B aligned
#define WS_WIN    461828   // 65536 int
#define WS_SORTED 527364   // 65536 int
#define WS_SCODE  592900   // 65536 int

// ---- output float layout ----
#define OFF_Q   0
#define OFF_IND 8388608
#define OFF_NCS 8454144
#define OFF_NEA 8455168
#define OFF_NE  8586240

#define LDST 136  // LDS row stride in bf16 units (128 + 8 pad)

static __device__ __forceinline__ unsigned short f2bf(float f) {
    unsigned u = __float_as_uint(f);
    unsigned r = (u + 0x7FFFu + ((u >> 16) & 1u)) >> 16;  // RTN-even
    return (unsigned short)r;
}

// ============ kernel 1: embed -> bf16 copy + shifted half-norms + ws zeroing ============
__global__ __launch_bounds__(64) void k_prep(const float* __restrict__ embed,
                                             unsigned short* __restrict__ ebf,
                                             float* __restrict__ en2,
                                             float* __restrict__ counts,
                                             float* __restrict__ esum) {
    int k = blockIdx.x;
    int l = threadIdx.x;
    if (l == 0) counts[k] = 0.0f;
    *(float2*)&esum[(size_t)k * DIM + l * 2] = (float2){0.0f, 0.0f};
    float2 v = *(const float2*)&embed[(size_t)k * DIM + l * 2];
    ushort2 b;
    b.x = f2bf(v.x);
    b.y = f2bf(v.y);
    *(ushort2*)&ebf[k * DIM + l * 2] = b;
    float s = v.x * v.x + v.y * v.y;
    #pragma unroll
    for (int off = 32; off; off >>= 1) s += __shfl_xor(s, off);
    if (l == 0) en2[k] = 512.0f - 0.5f * s;
}

// ============ kernel 2: fused scoring + rescore + hist + quantize ============
// (unchanged from round 3: 512 thr, 4 waves/SIMD, ping-pong e-tiles, 1 barrier/ct.
//  Round-3 lesson: doubling occupancy did NOT speed this kernel (56us both ways) --
//  it is not wave-starved; the session's remaining cost is the tail kernels.)
__global__ __launch_bounds__(512, 4) void k_fused(const float* __restrict__ x,
                                                  const float* __restrict__ embed,
                                                  const unsigned short* __restrict__ ebf,
                                                  const float* __restrict__ en2g,
                                                  int* __restrict__ win_g,
                                                  float* __restrict__ counts,
                                                  float* __restrict__ out) {
    __shared__ unsigned short buf[2][128 * LDST];  // ping-pong e-tiles; buf[0] stages x first
    __shared__ float en2s[KCODES];
    __shared__ int winS[128];

    const int tid = threadIdx.x;  // 0..511
    const int row0 = blockIdx.x * 128;

    #pragma unroll
    for (int i = 0; i < 2; ++i) en2s[i * 512 + tid] = en2g[i * 512 + tid];

    // ---- stage x tile (fp32 -> bf16) into buf[0] ----
    #pragma unroll
    for (int i = 0; i < 8; ++i) {
        int idx4 = i * 512 + tid;
        int lin = idx4 * 4;
        int r = lin >> 7, d = lin & 127;
        float4 v = *(const float4*)&x[(size_t)(row0 + r) * DIM + d];
        ushort4 b;
        b.x = f2bf(v.x); b.y = f2bf(v.y); b.z = f2bf(v.z); b.w = f2bf(v.w);
        *(ushort4*)&buf[0][r * LDST + d] = b;
    }
    __syncthreads();  // x tile visible

    const int lane = tid & 63;
    const int wv = tid >> 6;        // 0..7
    const int ch = wv & 1;          // code half (64 codes)
    const int rh = (wv >> 1) * 32;  // row base (32 rows per wave)
    const int l15 = lane & 15;
    const int q = lane >> 4;

    // ---- hoist A-fragments (ct-invariant) from buf[0] ----
    bf16x8 af[4][2];  // [ks][rt]
    #pragma unroll
    for (int ks = 0; ks < 4; ++ks)
        #pragma unroll
        for (int t = 0; t < 2; ++t)
            af[ks][t] = *(const bf16x8*)&buf[0][(rh + t * 16 + l15) * LDST + ks * 32 + q * 8];

    // ---- prologue: tile0 -> regs -> buf[1] ----
    uint4 er[4];
    #pragma unroll
    for (int i = 0; i < 4; ++i) {
        int idx8 = i * 512 + tid;
        int r = idx8 >> 4;
        int d = (idx8 & 15) * 8;
        er[i] = *(const uint4*)&ebf[(size_t)r * DIM + d];
    }
    #pragma unroll
    for (int i = 0; i < 4; ++i) {
        int idx8 = i * 512 + tid;
        int r = idx8 >> 4;
        int d = (idx8 & 15) * 8;
        *(uint4*)&buf[1][r * LDST + d] = er[i];
    }
    __syncthreads();  // tile0 ready; af reads of buf[0] complete

    float m1[2][4], m2[2][4];
    #pragma unroll
    for (int a = 0; a < 2; ++a)
        #pragma unroll
        for (int b = 0; b < 4; ++b) { m1[a][b] = 0.0f; m2[a][b] = 0.0f; }

    for (int ct = 0; ct < 8; ++ct) {
        const int c0 = ct * 128;
        const unsigned short* cbuf = buf[1 ^ (ct & 1)];  // tile ct lives here

        // issue next-tile loads early (latency hides under MFMA + tracking)
        if (ct < 7) {
            #pragma unroll
            for (int i = 0; i < 4; ++i) {
                int idx8 = i * 512 + tid;
                int r = idx8 >> 4;
                int d = (idx8 & 15) * 8;
                er[i] = *(const uint4*)&ebf[(size_t)(c0 + 128 + r) * DIM + d];
            }
        }

        // C-init = en2 (folds norm add into MFMA)
        f32x4 acc[2][4];
        #pragma unroll
        for (int cl = 0; cl < 4; ++cl) {
            float en = en2s[c0 + ch * 64 + cl * 16 + l15];
            #pragma unroll
            for (int rt = 0; rt < 2; ++rt) acc[rt][cl] = (f32x4){en, en, en, en};
        }

        #pragma unroll
        for (int ks = 0; ks < 4; ++ks) {
            bf16x8 bfr[4];
            #pragma unroll
            for (int cl = 0; cl < 4; ++cl)
                bfr[cl] = *(const bf16x8*)&cbuf[(ch * 64 + cl * 16 + l15) * LDST + ks * 32 + q * 8];
            #pragma unroll
            for (int rt = 0; rt < 2; ++rt)
                #pragma unroll
                for (int cl = 0; cl < 4; ++cl)
                    acc[rt][cl] = __builtin_amdgcn_mfma_f32_16x16x32_bf16(af[ks][rt], bfr[cl],
                                                                          acc[rt][cl], 0, 0, 0);
        }

        // top-2 tracking: 2 ops/value (med3 + max)
        #pragma unroll
        for (int cl = 0; cl < 4; ++cl) {
            unsigned cu = (unsigned)(c0 + ch * 64 + cl * 16 + l15);
            #pragma unroll
            for (int rt = 0; rt < 2; ++rt)
                #pragma unroll
                for (int rg = 0; rg < 4; ++rg) {
                    float s = acc[rt][cl][rg];
                    float kf = __uint_as_float((__float_as_uint(s) & ~1023u) | cu);
                    m2[rt][rg] = __builtin_amdgcn_fmed3f(m1[rt][rg], m2[rt][rg], kf);
                    m1[rt][rg] = fmaxf(m1[rt][rg], kf);
                }
        }

        // write next tile into the buffer whose reads ended at the previous barrier
        if (ct < 7) {
            unsigned short* nbuf = buf[ct & 1];
            #pragma unroll
            for (int i = 0; i < 4; ++i) {
                int idx8 = i * 512 + tid;
                int r = idx8 >> 4;
                int d = (idx8 & 15) * 8;
                *(uint4*)&nbuf[r * LDST + d] = er[i];
            }
        }
        __syncthreads();  // next tile ready / this tile's reads complete
    }

    // buf free: floats [0,512) = merge scratch, [512,1536) = histogram
    float* scratch = (float*)buf[0];
    unsigned* hist = (unsigned*)buf[0] + 512;

    #pragma unroll
    for (int rt = 0; rt < 2; ++rt)
        #pragma unroll
        for (int rg = 0; rg < 4; ++rg) {
            float a1 = m1[rt][rg], a2 = m2[rt][rg];
            #pragma unroll
            for (int off = 1; off <= 8; off <<= 1) {
                float o1 = __shfl_xor(a1, off);
                float o2 = __shfl_xor(a2, off);
                float t = fmaxf(a2, o2);
                a2 = __builtin_amdgcn_fmed3f(a1, o1, t);
                a1 = fmaxf(a1, o1);
            }
            if (l15 == 0) {
                int row = rh + rt * 16 + q * 4 + rg;
                scratch[row * 4 + ch * 2 + 0] = a1;
                scratch[row * 4 + ch * 2 + 1] = a2;
            }
        }

    #pragma unroll
    for (int i = 0; i < 2; ++i) hist[i * 512 + tid] = 0u;
    __syncthreads();  // S1: scratch + hist-zero visible

    // ---- fp64 exact rescore: 16 lanes/row ----
    {
        const int sub = tid & 15;
        const int g = tid >> 4;  // 0..31
        #pragma unroll 2
        for (int rr = 0; rr < 4; ++rr) {
            const int lrow = g * 4 + rr;
            const float* sp = &scratch[lrow * 4];
            int ci[4];
            ci[0] = (int)(__float_as_uint(sp[0]) & 1023u);
            ci[1] = (int)(__float_as_uint(sp[1]) & 1023u);
            ci[2] = (int)(__float_as_uint(sp[2]) & 1023u);
            ci[3] = (int)(__float_as_uint(sp[3]) & 1023u);

            const float* xr = &x[(size_t)(row0 + lrow) * DIM + sub * 4];
            float4 xa = *(const float4*)xr;
            float4 xb = *(const float4*)(xr + 64);

            double d[4];
            #pragma unroll
            for (int j = 0; j < 4; ++j) {
                const float* er2 = &embed[(size_t)ci[j] * DIM + sub * 4];
                float4 ea4 = *(const float4*)er2;
                float4 eb4 = *(const float4*)(er2 + 64);
                double t0 = (double)xa.x - (double)ea4.x;
                double t1 = (double)xa.y - (double)ea4.y;
                double t2 = (double)xa.z - (double)ea4.z;
                double t3 = (double)xa.w - (double)ea4.w;
                double t4 = (double)xb.x - (double)eb4.x;
                double t5 = (double)xb.y - (double)eb4.y;
                double t6 = (double)xb.z - (double)eb4.z;
                double t7 = (double)xb.w - (double)eb4.w;
                d[j] = ((t0 * t0 + t1 * t1) + (t2 * t2 + t3 * t3)) +
                       ((t4 * t4 + t5 * t5) + (t6 * t6 + t7 * t7));
            }
            #pragma unroll
            for (int off = 1; off <= 8; off <<= 1) {
                #pragma unroll
                for (int j = 0; j < 4; ++j) d[j] += __shfl_xor(d[j], off);
            }

            int win = ci[0];
            double dw = d[0];
            #pragma unroll
            for (int j = 1; j < 4; ++j) {
                bool b = (d[j] < dw) || (d[j] == dw && ci[j] < win);
                dw = b ? d[j] : dw;
                win = b ? ci[j] : win;
            }
            if (sub == 0) winS[lrow] = win;
        }
    }
    __syncthreads();  // S2: winS visible

    // ---- hist atomics + ind + win writes ----
    if (tid < 128) {
        int w = winS[tid];
        atomicAdd(&hist[w], 1u);
        win_g[row0 + tid] = w;
        out[OFF_IND + row0 + tid] = (float)w;
    }

    // ---- quantize gather + coalesced write (16 rows per wave) ----
    #pragma unroll 4
    for (int i = 0; i < 16; ++i) {
        int lrow = wv * 16 + i;
        int w = winS[lrow];  // wave-uniform
        float2 v = *(const float2*)&embed[(size_t)w * DIM + lane * 2];
        *(float2*)&out[OFF_Q + (size_t)(row0 + lrow) * DIM + lane * 2] = v;
    }

    __syncthreads();  // S3: hist atomics done
    #pragma unroll
    for (int i = 0; i < 2; ++i) {
        unsigned c = hist[i * 512 + tid];
        if (c) atomicAdd(&counts[i * 512 + tid], (float)c);
    }
}

// ============ kernel 4: shuffle-scan offsets + new_cluster_size + total ============
__global__ __launch_bounds__(1024) void k_offsets(const float* __restrict__ cs,
                                                  float* __restrict__ out,
                                                  float* __restrict__ ws) {
    __shared__ int wsum[16];
    __shared__ float wtot[16];
    const float* counts = ws + WS_COUNTS;
    int* ioff = (int*)(ws + WS_IOFF);

    int t = threadIdx.x;
    int lane = t & 63, w = t >> 6;
    float cf = counts[t];
    int c = (int)cf;
    float ncs = cs[t] * 0.99f + 0.01f * cf;
    out[OFF_NCS + t] = ncs;

    int v = c;
    #pragma unroll
    for (int off = 1; off < 64; off <<= 1) {
        int o = __shfl_up(v, off);
        if (lane >= off) v += o;
    }
    float nf = ncs;
    #pragma unroll
    for (int off = 32; off; off >>= 1) nf += __shfl_xor(nf, off);

    if (lane == 63) wsum[w] = v;
    if (lane == 0) wtot[w] = nf;
    __syncthreads();

    int base = 0;
    for (int i = 0; i < w; ++i) base += wsum[i];
    ioff[t] = base + v - c;

    if (t == 0) {
        float tt = 0.f;
        for (int i = 0; i < 16; ++i) tt += wtot[i];
        ws[WS_TOTAL] = tt;
    }
}

// ============ kernel 5: two-level scatter (atomic-serialization-proof) ============
// Round-3 lesson: per-row atomicAdd(&ioff[w],1) = ~8000 serialized same-address
// global RMWs on the hot bin (~50us, all pipes idle -- same failure mode the
// journal recorded for k_pick's histogram). Two-level version: LDS hist gives
// intra-block rank (LDS atomics, cheap), ONE global atomicAdd per (block,code)
// reserves the base chunk -> hot-bin global RMWs drop 8000 -> 64.
__global__ __launch_bounds__(1024) void k_sortscatter(const int* __restrict__ win_arr,
                                                      int* __restrict__ ioff,
                                                      int* __restrict__ sorted,
                                                      int* __restrict__ scode) {
    __shared__ int h[KCODES];
    __shared__ int bs[KCODES];
    const int t = threadIdx.x;
    h[t] = 0;
    __syncthreads();
    const int row = blockIdx.x * 1024 + t;
    const int w = win_arr[row];
    const int r = atomicAdd(&h[w], 1);  // intra-block rank
    __syncthreads();
    const int c = h[t];
    if (c) bs[t] = atomicAdd(&ioff[t], c);  // one global RMW per (block,code)
    __syncthreads();
    const int pos = bs[w] + r;
    sorted[pos] = row;
    scode[pos] = w;
}

// ============ kernel 6: run-length segment sum, 64-row chunks (skew-proof) ============
// Widened 16->64 rows per 16-lane group: same-address float RMWs on the hot
// code's esum addresses drop ~500 -> ~125.
__global__ __launch_bounds__(256) void k_segsum(const float* __restrict__ x,
                                                const int* __restrict__ sorted,
                                                const int* __restrict__ scode,
                                                float* __restrict__ esum) {
    const int lane = threadIdx.x & 63;
    const int wv = threadIdx.x >> 6;
    const int base = blockIdx.x * 256 + wv * 64;  // 64 rows per wave
    const int l15 = lane & 15;

    float ax = 0.f, ay = 0.f;
    int cur = -1;

    #pragma unroll
    for (int cc = 0; cc < 4; ++cc) {
        const int p = base + cc * 16 + l15;
        const int srow = sorted[p];
        const int sc = scode[p];
        if (cc == 0) cur = __shfl(sc, 0);
        #pragma unroll
        for (int j = 0; j < 16; ++j) {
            int row = __shfl(srow, j);
            int c = __shfl(sc, j);
            if (c != cur) {
                atomicAdd(&esum[cur * DIM + lane * 2], ax);
                atomicAdd(&esum[cur * DIM + lane * 2 + 1], ay);
                ax = 0.f; ay = 0.f;
                cur = c;
            }
            float2 v = *(const float2*)&x[(size_t)row * DIM + lane * 2];
            ax += v.x;
            ay += v.y;
        }
    }
    atomicAdd(&esum[cur * DIM + lane * 2], ax);
    atomicAdd(&esum[cur * DIM + lane * 2 + 1], ay);
}

// ============ kernel 7: new_embed_avg + new_embed ============
__global__ __launch_bounds__(256) void k_embed(const float* __restrict__ ea,
                                               const float* __restrict__ ws,
                                               float* __restrict__ out) {
    int i = blockIdx.x * 256 + threadIdx.x;
    int k = i >> 7;
    float nea = ea[i] * 0.99f + 0.01f * ws[WS_ESUM + i];
    out[OFF_NEA + i] = nea;
    float total = ws[WS_TOTAL];
    float ncs = out[OFF_NCS + k];
    float sm = (ncs + 1e-5f) / (total + 1024.0f * 1e-5f);
    out[OFF_NE + i] = nea / (sm * total);
}

extern "C" void kernel_launch(void* const* d_in, const int* in_sizes, int n_in,
                              void* d_out, int out_size, void* d_ws, size_t ws_size,
                              hipStream_t stream) {
    const float* x     = (const float*)d_in[0];
    const float* embed = (const float*)d_in[1];
    const float* cs    = (const float*)d_in[2];
    const float* ea    = (const float*)d_in[3];
    float* out = (float*)d_out;
    float* ws  = (float*)d_ws;

    k_prep<<<KCODES, 64, 0, stream>>>(embed, (unsigned short*)(ws + WS_EBF),
                                      ws + WS_ENORM2, ws + WS_COUNTS, ws + WS_ESUM);
    k_fused<<<NROWS / 128, 512, 0, stream>>>(x, embed,
                                             (const unsigned short*)(ws + WS_EBF),
                                             ws + WS_ENORM2, (int*)(ws + WS_WIN),
                                             ws + WS_COUNTS, out);
    k_offsets<<<1, 1024, 0, stream>>>(cs, out, ws);
    k_sortscatter<<<NROWS / 1024, 1024, 0, stream>>>((const int*)(ws + WS_WIN),
                                                     (int*)(ws + WS_IOFF),
                                                     (int*)(ws + WS_SORTED),
                                                     (int*)(ws + WS_SCODE));
    k_segsum<<<NROWS / 256, 256, 0, stream>>>(x, (const int*)(ws + WS_SORTED),
                                              (const int*)(ws + WS_SCODE), ws + WS_ESUM);
    k_embed<<<131072 / 256, 256, 0, stream>>>(ea, ws, out);
}

// Round 5
// 152.709 us; speedup vs baseline: 1.3430x; 1.0614x over previous
//
#include <hip/hip_runtime.h>
#include <math.h>

#define DIM 128
#define KCODES 1024
#define NROWS 65536

typedef short bf16x8 __attribute__((ext_vector_type(8)));
typedef float f32x4 __attribute__((ext_vector_type(4)));

// ---- workspace float-index layout ----
#define WS_COUNTS 0        // 1024 f: batch histogram (zeroed by k_prep)
#define WS_ESUM   1024     // 131072 f: segment sums (zeroed by k_prep)
#define WS_IOFF   132096   // 1024 int: per-code allocation cursor (zeroed by k_prep)
#define WS_TOTAL  133120   // 1 f
#define WS_ENORM2 133124   // 1024 f: 512 - 0.5*||e||^2
#define WS_EBF    134148   // 131072 bf16 (= 65536 float slots), 16B aligned
#define WS_WIN    461828   // 65536 int
#define WS_SORTED 527364   // 65536 int
#define WS_SCODE  592900   // 65536 int

// ---- output float layout ----
#define OFF_Q   0
#define OFF_IND 8388608
#define OFF_NCS 8454144
#define OFF_NEA 8455168
#define OFF_NE  8586240

static __device__ __forceinline__ unsigned short f2bf(float f) {
    unsigned u = __float_as_uint(f);
    unsigned r = (u + 0x7FFFu + ((u >> 16) & 1u)) >> 16;  // RTN-even
    return (unsigned short)r;
}

// ============ kernel 1: embed -> bf16 copy + shifted half-norms + ws zeroing ============
__global__ __launch_bounds__(64) void k_prep(const float* __restrict__ embed,
                                             unsigned short* __restrict__ ebf,
                                             float* __restrict__ en2,
                                             float* __restrict__ counts,
                                             float* __restrict__ esum,
                                             int* __restrict__ cursor) {
    int k = blockIdx.x;
    int l = threadIdx.x;
    if (l == 0) { counts[k] = 0.0f; cursor[k] = 0; }
    *(float2*)&esum[(size_t)k * DIM + l * 2] = (float2){0.0f, 0.0f};
    float2 v = *(const float2*)&embed[(size_t)k * DIM + l * 2];
    ushort2 b;
    b.x = f2bf(v.x);
    b.y = f2bf(v.y);
    *(ushort2*)&ebf[k * DIM + l * 2] = b;
    float s = v.x * v.x + v.y * v.y;
    #pragma unroll
    for (int off = 32; off; off >>= 1) s += __shfl_xor(s, off);
    if (l == 0) en2[k] = 512.0f - 0.5f * s;
}

// ============ kernel 2: fused scoring + rescore + hist + quantize ============
// Round-5 changes (k_fused was 56us with all pipes <=33% = latency-bound):
//  - T2: LDST 136->128 + XOR swizzle (idx ^ (row&7)<<3 in ushort units) on both
//    staging writes and fragment reads. Predicts BANK_CONFLICT 2.23M -> <0.3M.
//  - T5: s_setprio(1) around the MFMA+tracking cluster (ping-pong schedule has
//    wave role diversity -> scheduler has something to arbitrate).
//  - pairwise top-2: m2=max(m2,med3(a,b,m1)); m1=max(max(a,b),m1) -- exact,
//    2.5 VALU ops/value (was 3).
__global__ __launch_bounds__(512, 4) void k_fused(const float* __restrict__ x,
                                                  const float* __restrict__ embed,
                                                  const unsigned short* __restrict__ ebf,
                                                  const float* __restrict__ en2g,
                                                  int* __restrict__ win_g,
                                                  float* __restrict__ counts,
                                                  float* __restrict__ out) {
    __shared__ unsigned short buf[2][128 * 128];  // ping-pong; buf[0] stages x first
    __shared__ float en2s[KCODES];
    __shared__ int winS[128];

    const int tid = threadIdx.x;  // 0..511
    const int row0 = blockIdx.x * 128;

    #pragma unroll
    for (int i = 0; i < 2; ++i) en2s[i * 512 + tid] = en2g[i * 512 + tid];

    // ---- stage x tile (fp32 -> bf16) into buf[0], swizzled ----
    #pragma unroll
    for (int i = 0; i < 8; ++i) {
        int idx4 = i * 512 + tid;
        int lin = idx4 * 4;
        int r = lin >> 7, d = lin & 127;
        float4 v = *(const float4*)&x[(size_t)(row0 + r) * DIM + d];
        ushort4 b;
        b.x = f2bf(v.x); b.y = f2bf(v.y); b.z = f2bf(v.z); b.w = f2bf(v.w);
        *(ushort4*)&buf[0][(r * 128 + d) ^ ((r & 7) << 3)] = b;
    }
    __syncthreads();  // x tile visible

    const int lane = tid & 63;
    const int wv = tid >> 6;        // 0..7
    const int ch = wv & 1;          // code half (64 codes)
    const int rh = (wv >> 1) * 32;  // row base (32 rows per wave)
    const int l15 = lane & 15;
    const int q = lane >> 4;
    const int swz = (l15 & 7) << 3;  // fragment-row swizzle (rh, t*16 are 8-multiples)

    // ---- hoist A-fragments (ct-invariant) from buf[0] ----
    bf16x8 af[4][2];  // [ks][rt]
    #pragma unroll
    for (int ks = 0; ks < 4; ++ks)
        #pragma unroll
        for (int t = 0; t < 2; ++t)
            af[ks][t] = *(const bf16x8*)&buf[0][((rh + t * 16 + l15) * 128 + ks * 32 + q * 8) ^ swz];

    // ---- prologue: tile0 -> regs -> buf[1] ----
    uint4 er[4];
    #pragma unroll
    for (int i = 0; i < 4; ++i) {
        int idx8 = i * 512 + tid;
        int r = idx8 >> 4;
        int d = (idx8 & 15) * 8;
        er[i] = *(const uint4*)&ebf[(size_t)r * DIM + d];
    }
    #pragma unroll
    for (int i = 0; i < 4; ++i) {
        int idx8 = i * 512 + tid;
        int r = idx8 >> 4;
        int d = (idx8 & 15) * 8;
        *(uint4*)&buf[1][(r * 128 + d) ^ ((r & 7) << 3)] = er[i];
    }
    __syncthreads();  // tile0 ready; af reads of buf[0] complete

    float m1[2][4], m2[2][4];
    #pragma unroll
    for (int a = 0; a < 2; ++a)
        #pragma unroll
        for (int b = 0; b < 4; ++b) { m1[a][b] = 0.0f; m2[a][b] = 0.0f; }

    for (int ct = 0; ct < 8; ++ct) {
        const int c0 = ct * 128;
        const unsigned short* cbuf = buf[1 ^ (ct & 1)];  // tile ct lives here

        // issue next-tile loads early (latency hides under MFMA + tracking)
        if (ct < 7) {
            #pragma unroll
            for (int i = 0; i < 4; ++i) {
                int idx8 = i * 512 + tid;
                int r = idx8 >> 4;
                int d = (idx8 & 15) * 8;
                er[i] = *(const uint4*)&ebf[(size_t)(c0 + 128 + r) * DIM + d];
            }
        }

        // C-init = en2 (folds norm add into MFMA)
        f32x4 acc[2][4];
        #pragma unroll
        for (int cl = 0; cl < 4; ++cl) {
            float en = en2s[c0 + ch * 64 + cl * 16 + l15];
            #pragma unroll
            for (int rt = 0; rt < 2; ++rt) acc[rt][cl] = (f32x4){en, en, en, en};
        }

        __builtin_amdgcn_s_setprio(1);
        #pragma unroll
        for (int ks = 0; ks < 4; ++ks) {
            bf16x8 bfr[4];
            #pragma unroll
            for (int cl = 0; cl < 4; ++cl)
                bfr[cl] = *(const bf16x8*)&cbuf[((ch * 64 + cl * 16 + l15) * 128 + ks * 32 + q * 8) ^ swz];
            #pragma unroll
            for (int rt = 0; rt < 2; ++rt)
                #pragma unroll
                for (int cl = 0; cl < 4; ++cl)
                    acc[rt][cl] = __builtin_amdgcn_mfma_f32_16x16x32_bf16(af[ks][rt], bfr[cl],
                                                                          acc[rt][cl], 0, 0, 0);
        }

        // pairwise top-2 tracking: 5 ops / 2 values
        #pragma unroll
        for (int cp = 0; cp < 2; ++cp) {
            unsigned cu0 = (unsigned)(c0 + ch * 64 + cp * 32 + l15);
            unsigned cu1 = cu0 + 16u;
            #pragma unroll
            for (int rt = 0; rt < 2; ++rt)
                #pragma unroll
                for (int rg = 0; rg < 4; ++rg) {
                    float sa = acc[rt][cp * 2][rg];
                    float sb = acc[rt][cp * 2 + 1][rg];
                    float a = __uint_as_float((__float_as_uint(sa) & ~1023u) | cu0);
                    float b = __uint_as_float((__float_as_uint(sb) & ~1023u) | cu1);
                    m2[rt][rg] = fmaxf(m2[rt][rg],
                                       __builtin_amdgcn_fmed3f(a, b, m1[rt][rg]));
                    m1[rt][rg] = fmaxf(fmaxf(a, b), m1[rt][rg]);
                }
        }
        __builtin_amdgcn_s_setprio(0);

        // write next tile into the buffer whose reads ended at the previous barrier
        if (ct < 7) {
            unsigned short* nbuf = buf[ct & 1];
            #pragma unroll
            for (int i = 0; i < 4; ++i) {
                int idx8 = i * 512 + tid;
                int r = idx8 >> 4;
                int d = (idx8 & 15) * 8;
                *(uint4*)&nbuf[(r * 128 + d) ^ ((r & 7) << 3)] = er[i];
            }
        }
        __syncthreads();  // next tile ready / this tile's reads complete
    }

    // buf free: floats [0,512) = merge scratch, [512,1536) = histogram
    float* scratch = (float*)buf[0];
    unsigned* hist = (unsigned*)buf[0] + 512;

    #pragma unroll
    for (int rt = 0; rt < 2; ++rt)
        #pragma unroll
        for (int rg = 0; rg < 4; ++rg) {
            float a1 = m1[rt][rg], a2 = m2[rt][rg];
            #pragma unroll
            for (int off = 1; off <= 8; off <<= 1) {
                float o1 = __shfl_xor(a1, off);
                float o2 = __shfl_xor(a2, off);
                float t = fmaxf(a2, o2);
                a2 = __builtin_amdgcn_fmed3f(a1, o1, t);
                a1 = fmaxf(a1, o1);
            }
            if (l15 == 0) {
                int row = rh + rt * 16 + q * 4 + rg;
                scratch[row * 4 + ch * 2 + 0] = a1;
                scratch[row * 4 + ch * 2 + 1] = a2;
            }
        }

    #pragma unroll
    for (int i = 0; i < 2; ++i) hist[i * 512 + tid] = 0u;
    __syncthreads();  // S1: scratch + hist-zero visible

    // ---- fp64 exact rescore: 16 lanes/row ----
    {
        const int sub = tid & 15;
        const int g = tid >> 4;  // 0..31
        #pragma unroll 2
        for (int rr = 0; rr < 4; ++rr) {
            const int lrow = g * 4 + rr;
            const float* sp = &scratch[lrow * 4];
            int ci[4];
            ci[0] = (int)(__float_as_uint(sp[0]) & 1023u);
            ci[1] = (int)(__float_as_uint(sp[1]) & 1023u);
            ci[2] = (int)(__float_as_uint(sp[2]) & 1023u);
            ci[3] = (int)(__float_as_uint(sp[3]) & 1023u);

            const float* xr = &x[(size_t)(row0 + lrow) * DIM + sub * 4];
            float4 xa = *(const float4*)xr;
            float4 xb = *(const float4*)(xr + 64);

            double d[4];
            #pragma unroll
            for (int j = 0; j < 4; ++j) {
                const float* er2 = &embed[(size_t)ci[j] * DIM + sub * 4];
                float4 ea4 = *(const float4*)er2;
                float4 eb4 = *(const float4*)(er2 + 64);
                double t0 = (double)xa.x - (double)ea4.x;
                double t1 = (double)xa.y - (double)ea4.y;
                double t2 = (double)xa.z - (double)ea4.z;
                double t3 = (double)xa.w - (double)ea4.w;
                double t4 = (double)xb.x - (double)eb4.x;
                double t5 = (double)xb.y - (double)eb4.y;
                double t6 = (double)xb.z - (double)eb4.z;
                double t7 = (double)xb.w - (double)eb4.w;
                d[j] = ((t0 * t0 + t1 * t1) + (t2 * t2 + t3 * t3)) +
                       ((t4 * t4 + t5 * t5) + (t6 * t6 + t7 * t7));
            }
            #pragma unroll
            for (int off = 1; off <= 8; off <<= 1) {
                #pragma unroll
                for (int j = 0; j < 4; ++j) d[j] += __shfl_xor(d[j], off);
            }

            int win = ci[0];
            double dw = d[0];
            #pragma unroll
            for (int j = 1; j < 4; ++j) {
                bool b = (d[j] < dw) || (d[j] == dw && ci[j] < win);
                dw = b ? d[j] : dw;
                win = b ? ci[j] : win;
            }
            if (sub == 0) winS[lrow] = win;
        }
    }
    __syncthreads();  // S2: winS visible

    // ---- hist atomics + ind + win writes ----
    if (tid < 128) {
        int w = winS[tid];
        atomicAdd(&hist[w], 1u);
        win_g[row0 + tid] = w;
        out[OFF_IND + row0 + tid] = (float)w;
    }

    // ---- quantize gather + coalesced write (16 rows per wave) ----
    #pragma unroll 4
    for (int i = 0; i < 16; ++i) {
        int lrow = wv * 16 + i;
        int w = winS[lrow];  // wave-uniform
        float2 v = *(const float2*)&embed[(size_t)w * DIM + lane * 2];
        *(float2*)&out[OFF_Q + (size_t)(row0 + lrow) * DIM + lane * 2] = v;
    }

    __syncthreads();  // S3: hist atomics done
    #pragma unroll
    for (int i = 0; i < 2; ++i) {
        unsigned c = hist[i * 512 + tid];
        if (c) atomicAdd(&counts[i * 512 + tid], (float)c);
    }
}

// ============ kernel 3: scan + scatter in ONE kernel (merged k_offsets) ============
// Every block redundantly computes the 1024-bin exclusive scan from counts (4KB
// L2 read + LDS scan, ~trivial), then allocates its chunk with a ZERO-based
// cursor: bs = scan_base[code] + atomicAdd(&cursor[code], cnt). Hot-bin global
// RMWs stay at <=64 per code. Block 0 also writes NCS + total (absorbs k_offsets).
// Net: one fewer dispatch (~8-10us of launch/gap overhead).
__global__ __launch_bounds__(1024) void k_scansort(const float* __restrict__ cs,
                                                   const int* __restrict__ win_arr,
                                                   float* __restrict__ ws,
                                                   int* __restrict__ sorted,
                                                   int* __restrict__ scode,
                                                   float* __restrict__ out) {
    __shared__ int h[KCODES];
    __shared__ int bs[KCODES];
    __shared__ int wsum[16];
    __shared__ float wtot[16];
    const float* counts = ws + WS_COUNTS;
    int* cursor = (int*)(ws + WS_IOFF);

    const int t = threadIdx.x;
    h[t] = 0;
    __syncthreads();
    const int row = blockIdx.x * 1024 + t;
    const int w = win_arr[row];
    const int r = atomicAdd(&h[w], 1);  // intra-block rank (LDS, cheap)

    // redundant global exclusive scan of counts
    const int lane = t & 63, wvi = t >> 6;
    const float cf = counts[t];
    const int c = (int)cf;
    int v = c;
    #pragma unroll
    for (int off = 1; off < 64; off <<= 1) {
        int o = __shfl_up(v, off);
        if (lane >= off) v += o;
    }
    if (lane == 63) wsum[wvi] = v;
    if (blockIdx.x == 0) {
        float ncs = cs[t] * 0.99f + 0.01f * cf;
        out[OFF_NCS + t] = ncs;
        float nf = ncs;
        #pragma unroll
        for (int off = 32; off; off >>= 1) nf += __shfl_xor(nf, off);
        if (lane == 0) wtot[wvi] = nf;
    }
    __syncthreads();  // h counts + wsum (+ wtot) ready

    int base = 0;
    for (int i = 0; i < wvi; ++i) base += wsum[i];
    const int gbase = base + v - c;  // global exclusive base for code t

    if (blockIdx.x == 0 && t == 0) {
        float tt = 0.f;
        for (int i = 0; i < 16; ++i) tt += wtot[i];
        ws[WS_TOTAL] = tt;
    }

    const int cnt = h[t];
    if (cnt) bs[t] = gbase + atomicAdd(&cursor[t], cnt);  // one global RMW per (block,code)
    __syncthreads();
    const int pos = bs[w] + r;
    sorted[pos] = row;
    scode[pos] = w;
}

// ============ kernel 4: run-length segment sum, 64-row chunks (skew-proof) ============
__global__ __launch_bounds__(256) void k_segsum(const float* __restrict__ x,
                                                const int* __restrict__ sorted,
                                                const int* __restrict__ scode,
                                                float* __restrict__ esum) {
    const int lane = threadIdx.x & 63;
    const int wv = threadIdx.x >> 6;
    const int base = blockIdx.x * 256 + wv * 64;  // 64 rows per wave
    const int l15 = lane & 15;

    float ax = 0.f, ay = 0.f;
    int cur = -1;

    #pragma unroll
    for (int cc = 0; cc < 4; ++cc) {
        const int p = base + cc * 16 + l15;
        const int srow = sorted[p];
        const int sc = scode[p];
        if (cc == 0) cur = __shfl(sc, 0);
        #pragma unroll
        for (int j = 0; j < 16; ++j) {
            int row = __shfl(srow, j);
            int c = __shfl(sc, j);
            if (c != cur) {
                atomicAdd(&esum[cur * DIM + lane * 2], ax);
                atomicAdd(&esum[cur * DIM + lane * 2 + 1], ay);
                ax = 0.f; ay = 0.f;
                cur = c;
            }
            float2 v = *(const float2*)&x[(size_t)row * DIM + lane * 2];
            ax += v.x;
            ay += v.y;
        }
    }
    atomicAdd(&esum[cur * DIM + lane * 2], ax);
    atomicAdd(&esum[cur * DIM + lane * 2 + 1], ay);
}

// ============ kernel 5: new_embed_avg + new_embed ============
__global__ __launch_bounds__(256) void k_embed(const float* __restrict__ ea,
                                               const float* __restrict__ ws,
                                               float* __restrict__ out) {
    int i = blockIdx.x * 256 + threadIdx.x;
    int k = i >> 7;
    float nea = ea[i] * 0.99f + 0.01f * ws[WS_ESUM + i];
    out[OFF_NEA + i] = nea;
    float total = ws[WS_TOTAL];
    float ncs = out[OFF_NCS + k];
    float sm = (ncs + 1e-5f) / (total + 1024.0f * 1e-5f);
    out[OFF_NE + i] = nea / (sm * total);
}

extern "C" void kernel_launch(void* const* d_in, const int* in_sizes, int n_in,
                              void* d_out, int out_size, void* d_ws, size_t ws_size,
                              hipStream_t stream) {
    const float* x     = (const float*)d_in[0];
    const float* embed = (const float*)d_in[1];
    const float* cs    = (const float*)d_in[2];
    const float* ea    = (const float*)d_in[3];
    float* out = (float*)d_out;
    float* ws  = (float*)d_ws;

    k_prep<<<KCODES, 64, 0, stream>>>(embed, (unsigned short*)(ws + WS_EBF),
                                      ws + WS_ENORM2, ws + WS_COUNTS, ws + WS_ESUM,
                                      (int*)(ws + WS_IOFF));
    k_fused<<<NROWS / 128, 512, 0, stream>>>(x, embed,
                                             (const unsigned short*)(ws + WS_EBF),
                                             ws + WS_ENORM2, (int*)(ws + WS_WIN),
                                             ws + WS_COUNTS, out);
    k_scansort<<<NROWS / 1024, 1024, 0, stream>>>(cs, (const int*)(ws + WS_WIN), ws,
                                                  (int*)(ws + WS_SORTED),
                                                  (int*)(ws + WS_SCODE), out);
    k_segsum<<<NROWS / 256, 256, 0, stream>>>(x, (const int*)(ws + WS_SORTED),
                                              (const int*)(ws + WS_SCODE), ws + WS_ESUM);
    k_embed<<<131072 / 256, 256, 0, stream>>>(ea, ws, out);
}